// Round 6
// baseline (443.549 us; speedup 1.0000x reference)
//
#include <hip/hip_runtime.h>
#include <math.h>

// ---------------------------------------------------------------------------
// ClusterML MEGA-KERNEL (round 6 = round 5 + FIXED grid barrier).
//   r5 post-mortem: spin loop was atomicAdd(bar,0) — device-scope RMW from
//   512 spinners serializing on one cacheline at the coherence point
//   (~100us/barrier; MfmaUtil 1.7 / VALU 4.9 / HBM 7.5% all diluted).
//   Fix: arrive-once atomicAdd + last-arriver sets a release FLAG on a
//   separate cacheline; spinners use __hip_atomic_load (no RMW, loads
//   don't need exclusive ownership). Everything else identical to r5.
// ---------------------------------------------------------------------------

typedef __bf16 bf16;
typedef bf16  bf16x2 __attribute__((ext_vector_type(2)));
typedef bf16  bf16x4 __attribute__((ext_vector_type(4)));
typedef bf16  bf16x8 __attribute__((ext_vector_type(8)));
typedef float f32x4  __attribute__((ext_vector_type(4)));

#define B_ROWS 131072
#define K_DIM  512
#define E_DIM  128
#define C_CLS  64

#define BM 128
#define BK 64

#define GRID 512
#define ROWS_PER_SEG (B_ROWS / GRID)         // 256

// two-cell grid barrier: arrive (1 RMW/block) + flag spin (loads only).
// bar and flag live on separate cachelines; both zeroed per call.
__device__ __forceinline__ void grid_sync(unsigned* bar, unsigned* flag,
                                          unsigned phase)
{
    __syncthreads();                       // block's phase work done
    if (threadIdx.x == 0) {
        __threadfence();                   // release: make writes visible
        unsigned old = __hip_atomic_fetch_add(bar, 1u, __ATOMIC_ACQ_REL,
                                              __HIP_MEMORY_SCOPE_AGENT);
        if (old == phase * GRID - 1u) {
            __hip_atomic_store(flag, phase, __ATOMIC_RELEASE,
                               __HIP_MEMORY_SCOPE_AGENT);
        } else {
            while (__hip_atomic_load(flag, __ATOMIC_ACQUIRE,
                                     __HIP_MEMORY_SCOPE_AGENT) < phase)
                __builtin_amdgcn_s_sleep(4);
        }
    }
    __syncthreads();
    __threadfence();                       // acquire for all threads
}

__global__ __launch_bounds__(256, 2)
void mega_kernel(const float* __restrict__ x, const int* __restrict__ y,
                 const float* __restrict__ W, const float* __restrict__ bias,
                 const float* __restrict__ centroid0,
                 bf16* __restrict__ outb, float* __restrict__ rnorm,
                 float* __restrict__ pw, float* __restrict__ pc,
                 float* __restrict__ sums, float* __restrict__ cntg,
                 float* __restrict__ out0, float* __restrict__ proto,
                 unsigned* __restrict__ bar, unsigned* __restrict__ flag)
{
    __shared__ __align__(16) char smem[65536];
    const int t    = threadIdx.x;
    const int lane = t & 63;
    const int w    = t >> 6;

    // ===================== Phase 1: out = bf16(x@W^T + b), rnorm ==========
    {
        bf16* As = (bf16*)smem;            // [2][8192] bf16 (32KB)
        bf16* Bs = (bf16*)(smem + 32768);  // [2][8192] bf16 (32KB)
        const int wr = w >> 1, wc = w & 1;
        const int fr = lane & 15, fq = lane >> 4;
        const int srow = t >> 4;           // 0..15
        const int scol = (t & 15) * 4;     // 0..60

        for (int rep = 0; rep < 2; ++rep) {
            const int  tile = blockIdx.x + rep * GRID;
            const long blockRow = (long)tile * BM;
            const float* xg = x + blockRow * K_DIM;
            f32x4 acc[4][4] = {};
            f32x4 va[8], vb[8];

            __syncthreads();               // smem reuse guard (lr of prev rep)
            #pragma unroll
            for (int r = 0; r < 8; ++r) {
                int row = r * 16 + srow;
                va[r] = *(const f32x4*)(xg + (long)row * K_DIM + scol);
                vb[r] = *(const f32x4*)(W  + (long)row * K_DIM + scol);
            }
            #pragma unroll
            for (int r = 0; r < 8; ++r) {
                int row = r * 16 + srow;
                bf16x4 pa = { (bf16)va[r].x, (bf16)va[r].y, (bf16)va[r].z, (bf16)va[r].w };
                bf16x4 pb = { (bf16)vb[r].x, (bf16)vb[r].y, (bf16)vb[r].z, (bf16)vb[r].w };
                int byte = row * (BK * 2) + ((scol * 2) ^ ((row & 7) << 4));
                *(bf16x4*)((char*)As + byte) = pa;
                *(bf16x4*)((char*)Bs + byte) = pb;
            }
            __syncthreads();

            for (int kti = 0; kti < K_DIM / BK; ++kti) {
                const int p = kti & 1;
                if (kti < K_DIM / BK - 1) {
                    const int kt = (kti + 1) * BK;
                    #pragma unroll
                    for (int r = 0; r < 8; ++r) {
                        int row = r * 16 + srow;
                        va[r] = *(const f32x4*)(xg + (long)row * K_DIM + kt + scol);
                        vb[r] = *(const f32x4*)(W  + (long)row * K_DIM + kt + scol);
                    }
                }
                const char* Ap = (const char*)As + p * 16384;
                const char* Bp = (const char*)Bs + p * 16384;
                #pragma unroll
                for (int kk = 0; kk < 2; ++kk) {
                    bf16x8 af[4], bg[4];
                    #pragma unroll
                    for (int m = 0; m < 4; ++m) {
                        int row  = wr * 64 + m * 16 + fr;
                        int byte = row * (BK * 2) + (((kk * 32 + fq * 8) * 2) ^ ((row & 7) << 4));
                        af[m] = *(const bf16x8*)(Ap + byte);
                    }
                    #pragma unroll
                    for (int n = 0; n < 4; ++n) {
                        int row  = wc * 64 + n * 16 + fr;
                        int byte = row * (BK * 2) + (((kk * 32 + fq * 8) * 2) ^ ((row & 7) << 4));
                        bg[n] = *(const bf16x8*)(Bp + byte);
                    }
                    #pragma unroll
                    for (int m = 0; m < 4; ++m)
                        #pragma unroll
                        for (int n = 0; n < 4; ++n)
                            acc[m][n] = __builtin_amdgcn_mfma_f32_16x16x32_bf16(
                                af[m], bg[n], acc[m][n], 0, 0, 0);
                }
                if (kti < K_DIM / BK - 1) {
                    #pragma unroll
                    for (int r = 0; r < 8; ++r) {
                        int row = r * 16 + srow;
                        bf16x4 pa = { (bf16)va[r].x, (bf16)va[r].y, (bf16)va[r].z, (bf16)va[r].w };
                        bf16x4 pb = { (bf16)vb[r].x, (bf16)vb[r].y, (bf16)vb[r].z, (bf16)vb[r].w };
                        int byte = row * (BK * 2) + ((scol * 2) ^ ((row & 7) << 4));
                        *(bf16x4*)((char*)As + (p ^ 1) * 16384 + byte) = pa;
                        *(bf16x4*)((char*)Bs + (p ^ 1) * 16384 + byte) = pb;
                    }
                    __syncthreads();
                }
            }

            // epilogue: C/D layout col = lane&15, row = (lane>>4)*4 + j
            __syncthreads();
            float* lr = (float*)smem;      // overlaps As buf0 (dead now)
            if (t < BM) lr[t] = 0.f;
            __syncthreads();
            float bvv[4];
            #pragma unroll
            for (int n = 0; n < 4; ++n) bvv[n] = bias[wc * 64 + n * 16 + fr];
            #pragma unroll
            for (int m = 0; m < 4; ++m) {
                #pragma unroll
                for (int j = 0; j < 4; ++j) {
                    long grow = blockRow + wr * 64 + m * 16 + fq * 4 + j;
                    float s = 0.f;
                    #pragma unroll
                    for (int n = 0; n < 4; ++n) {
                        float v = acc[m][n][j] + bvv[n];
                        outb[grow * E_DIM + wc * 64 + n * 16 + fr] = (bf16)v;
                        s += v * v;
                    }
                    s += __shfl_xor(s, 1); s += __shfl_xor(s, 2);
                    s += __shfl_xor(s, 4); s += __shfl_xor(s, 8);
                    if (fr == 0) atomicAdd(&lr[wr * 64 + m * 16 + fq * 4 + j], s);
                }
            }
            __syncthreads();
            if (t < BM) rnorm[blockRow + t] = lr[t];
        }
    }
    grid_sync(bar, flag, 1);

    // ===================== Phase 2: per-class partial sums ================
    {
        float* lsum = (float*)smem;               // 32KB
        float* lcnt = (float*)(smem + 32768);     // 256B
        int*   ly   = (int*)(smem + 33024);       // 1KB
        for (int i = t; i < C_CLS * E_DIM; i += 256) lsum[i] = 0.f;
        if (t < C_CLS) lcnt[t] = 0.f;
        const long base = (long)blockIdx.x * ROWS_PER_SEG;
        if (t < ROWS_PER_SEG) ly[t] = y[base + t];
        __syncthreads();
        #pragma unroll 4
        for (int i = w; i < ROWS_PER_SEG; i += 4) {
            int cls = ly[i];
            bf16x2 v = *(const bf16x2*)(outb + (base + i) * E_DIM + lane * 2);
            atomicAdd(&lsum[cls * E_DIM + lane * 2 + 0], (float)v[0]);
            atomicAdd(&lsum[cls * E_DIM + lane * 2 + 1], (float)v[1]);
            if (lane == 0) atomicAdd(&lcnt[cls], 1.f);
        }
        __syncthreads();
        for (int i = t; i < C_CLS * E_DIM; i += 256)
            pw[(long)blockIdx.x * (C_CLS * E_DIM) + i] = lsum[i];
        if (t < C_CLS) pc[blockIdx.x * C_CLS + t] = lcnt[t];
    }
    grid_sync(bar, flag, 2);

    // ===================== Phase 3: reduce partials + counts ==============
    {
        float* scr = (float*)smem;
        const int i16 = t & 15, slice = t >> 4;       // 16 idx x 16 slices
        const int idx = blockIdx.x * 16 + i16;
        float s = 0.f;
        #pragma unroll 8
        for (int j = slice * 32; j < slice * 32 + 32; ++j)
            s += pw[(long)j * (C_CLS * E_DIM) + idx];
        scr[slice * 16 + i16] = s;
        __syncthreads();
        if (t < 16) {
            float r = 0.f;
            #pragma unroll
            for (int k = 0; k < 16; ++k) r += scr[k * 16 + t];
            sums[blockIdx.x * 16 + t] = r;
        }
        if (blockIdx.x < C_CLS) {                     // counts for class c
            __syncthreads();
            int c = blockIdx.x;
            scr[t] = pc[t * C_CLS + c] + pc[(t + 256) * C_CLS + c];
            __syncthreads();
            for (int st = 128; st > 0; st >>= 1) {
                if (t < st) scr[t] += scr[t + st];
                __syncthreads();
            }
            if (t == 0) cntg[c] = scr[0];
        }
    }
    grid_sync(bar, flag, 3);

    // ===================== Phase 4: centroids + dist + proto ==============
    {
        float* centf  = (float*)smem;                 // [64][129] f32 (33024B)
        float* cnormS = (float*)(smem + 33024);       // [64]
        bf16*  Cs     = (bf16*)(smem + 33280);        // [64][128] swizzled bf16
        float* srn    = (float*)(smem + 49664);       // [128]
        float* scr2   = (float*)(smem + 50176);       // [256]

        for (int i = t; i < C_CLS * E_DIM; i += 256) {
            int cc = i >> 7, e = i & 127;
            float v = centroid0[i] + sums[i] / cntg[cc];
            centf[cc * 129 + e] = v;
            int byte = cc * 256 + ((e * 2) ^ ((cc & 7) << 4));
            *(bf16*)((char*)Cs + byte) = (bf16)v;
        }
        __syncthreads();
        {
            int c = t >> 2, q = t & 3;
            float sSum = 0.f;
            #pragma unroll 8
            for (int e = q * 32; e < q * 32 + 32; ++e) {
                float v = centf[c * 129 + e];
                sSum += v * v;
            }
            scr2[t] = sSum;
        }
        __syncthreads();
        if (t < C_CLS)
            cnormS[t] = scr2[4 * t] + scr2[4 * t + 1] + scr2[4 * t + 2] + scr2[4 * t + 3];

        const int fr = lane & 15, fq = lane >> 4;
        for (int rep = 0; rep < 2; ++rep) {
            const long blkrow = (long)(blockIdx.x + rep * GRID) * 128;
            __syncthreads();               // cnormS/Cs visible; srn reuse guard
            if (t < 32) ((f32x4*)srn)[t] = ((const f32x4*)(rnorm + blkrow))[t];
            __syncthreads();
            f32x4 acc[2][4] = {};
            #pragma unroll
            for (int kt = 0; kt < 4; ++kt) {
                bf16x8 af[2];
                #pragma unroll
                for (int m = 0; m < 2; ++m) {
                    long row = blkrow + w * 32 + m * 16 + fr;
                    af[m] = *(const bf16x8*)(outb + row * E_DIM + kt * 32 + fq * 8);
                }
                #pragma unroll
                for (int n = 0; n < 4; ++n) {
                    int row  = n * 16 + fr;
                    int byte = row * (E_DIM * 2) + (((kt * 32 + fq * 8) * 2) ^ ((row & 7) << 4));
                    bf16x8 bq = *(const bf16x8*)((const char*)Cs + byte);
                    acc[0][n] = __builtin_amdgcn_mfma_f32_16x16x32_bf16(af[0], bq, acc[0][n], 0, 0, 0);
                    acc[1][n] = __builtin_amdgcn_mfma_f32_16x16x32_bf16(af[1], bq, acc[1][n], 0, 0, 0);
                }
            }
            #pragma unroll
            for (int m = 0; m < 2; ++m) {
                #pragma unroll
                for (int n = 0; n < 4; ++n) {
                    int gcol = n * 16 + fr;
                    float cn = cnormS[gcol];
                    #pragma unroll
                    for (int j = 0; j < 4; ++j) {
                        int lrow = w * 32 + m * 16 + fq * 4 + j;
                        float d2 = srn[lrow] + cn - 2.f * acc[m][n][j];
                        float dist = sqrtf(fmaxf(d2, 1e-12f));
                        float ez = __expf(-0.5f * dist);
                        out0[(blkrow + lrow) * C_CLS + gcol] = 1.f / (1.f + __expf(-ez));
                    }
                }
            }
        }
        if (blockIdx.x < 16) {                       // fused proto_dist
            int p = blockIdx.x * 256 + t;
            int i = p >> 6, j = p & 63;
            float d = 0.f;
            #pragma unroll 4
            for (int e = 0; e < E_DIM; ++e)
                d += centf[i * 129 + e] * centf[j * 129 + e];
            float d2 = cnormS[i] + cnormS[j] - 2.f * d;
            proto[p] = __expf(-0.5f * sqrtf(fmaxf(d2, 1e-12f)));
        }
    }
}

// ---------------------------------------------------------------------------
extern "C" void kernel_launch(void* const* d_in, const int* in_sizes, int n_in,
                              void* d_out, int out_size, void* d_ws, size_t ws_size,
                              hipStream_t stream)
{
    const float* x         = (const float*)d_in[0];
    const int*   y         = (const int*)d_in[1];
    const float* W         = (const float*)d_in[2];
    const float* bias      = (const float*)d_in[3];
    const float* centroid0 = (const float*)d_in[4];

    char* ws = (char*)d_ws;
    bf16*  outb  = (bf16*)ws;                                   // 33,554,432 B
    float* rnorm = (float*)(ws + 33554432);                     //    524,288 B
    float* pw    = (float*)(ws + 34078720);                     // 16,777,216 B
    float* pc    = (float*)(ws + 50855936);                     //    131,072 B
    float* sums  = (float*)(ws + 50987008);                     //     32,768 B
    float* cntg  = (float*)(ws + 51019776);                     //        256 B
    unsigned* bar  = (unsigned*)(ws + 51020032);                // cacheline 0
    unsigned* flag = (unsigned*)(ws + 51020160);                // cacheline 1

    float* out0  = (float*)d_out;
    float* proto = out0 + (long)B_ROWS * C_CLS;

    hipMemsetAsync(bar, 0, 256, stream);   // zeroes bar AND flag
    hipLaunchKernelGGL(mega_kernel, dim3(GRID), dim3(256), 0, stream,
                       x, y, W, bias, centroid0,
                       outb, rnorm, pw, pc, sums, cntg, out0, proto, bar, flag);
}

// Round 7
// 299.174 us; speedup vs baseline: 1.4826x; 1.4826x over previous
//
#include <hip/hip_runtime.h>
#include <math.h>

// ---------------------------------------------------------------------------
// ClusterML pipeline (round 7): 3-launch hierarchical fusion, NO grid sync.
//   r5/r6 post-mortem: persistent kernel w/ device barriers = 480us of idle
//   (structure pathological); reverted. r4 attribution: per-launch ~15us,
//   segsum re-read avoidable -> fuse segsum INTO gemm (block rows == segment).
//   A: gemm 2 tiles/blk + per-class partials from acc regs  (512 blocks)
//   B: reduce 1024 partials + counts + centroids + cnorm    (64 blocks)
//   C: dist + sigmoid + fused proto_dist                    (1040 blocks)
// ---------------------------------------------------------------------------

typedef __bf16 bf16;
typedef bf16  bf16x4 __attribute__((ext_vector_type(4)));
typedef bf16  bf16x8 __attribute__((ext_vector_type(8)));
typedef float f32x4  __attribute__((ext_vector_type(4)));

#define B_ROWS 131072
#define K_DIM  512
#define E_DIM  128
#define C_CLS  64

#define BM 128
#define BK 64

#define GRID_A 512                           // 2 tiles per block
#define N_TILES 1024

#define DIST_BLOCKS (B_ROWS / 128)           // 1024
#define PROTO_BLOCKS 16

// -------------------- Kernel A: gemm + rnorm + per-class partials ----------
// LDS map: As dbuf [0,32K) | Bs dbuf [32K,64K) | ly 256 ints [64K,65K)
//          lr 128 f32 [65K,65.5K) | lsum overlaps As [0,32K) | lcnt [32K,+256)
__global__ __launch_bounds__(256, 2)
void gemmseg_kernel(const float* __restrict__ x, const int* __restrict__ y,
                    const float* __restrict__ W, const float* __restrict__ bias,
                    bf16* __restrict__ outb, float* __restrict__ rnorm,
                    float* __restrict__ pw, float* __restrict__ pc)
{
    __shared__ __align__(16) char smem[67072];
    bf16*  As   = (bf16*)smem;                 // [2][8192]
    bf16*  Bs   = (bf16*)(smem + 32768);       // [2][8192]
    int*   ly   = (int*)(smem + 65536);        // [256]
    float* lr   = (float*)(smem + 66560);      // [128]
    float* lsum = (float*)smem;                // overlaps As (dead at epilogue)
    float* lcnt = (float*)(smem + 32768);      // overlaps Bs (dead at epilogue)

    const int t    = threadIdx.x;
    const int lane = t & 63;
    const int w    = t >> 6;
    const int wr   = w >> 1, wc = w & 1;
    const int fr   = lane & 15, fq = lane >> 4;
    const int srow = t >> 4;                   // 0..15
    const int scol = (t & 15) * 4;             // 0..60

    const long baseRow = (long)blockIdx.x * 256;
    if (t < 256) ly[t] = y[baseRow + t];

    float bvv[4];
    #pragma unroll
    for (int n = 0; n < 4; ++n) bvv[n] = bias[wc * 64 + n * 16 + fr];

    for (int rep = 0; rep < 2; ++rep) {
        const int  tile = blockIdx.x * 2 + rep;
        const long blockRow = (long)tile * BM;
        const float* xg = x + blockRow * K_DIM;
        f32x4 acc[4][4] = {};
        f32x4 va[8], vb[8];

        __syncthreads();                       // LDS reuse guard (prev epilogue)
        #pragma unroll
        for (int r = 0; r < 8; ++r) {
            int row = r * 16 + srow;
            va[r] = *(const f32x4*)(xg + (long)row * K_DIM + scol);
            vb[r] = *(const f32x4*)(W  + (long)row * K_DIM + scol);
        }
        #pragma unroll
        for (int r = 0; r < 8; ++r) {
            int row = r * 16 + srow;
            bf16x4 pa = { (bf16)va[r].x, (bf16)va[r].y, (bf16)va[r].z, (bf16)va[r].w };
            bf16x4 pb = { (bf16)vb[r].x, (bf16)vb[r].y, (bf16)vb[r].z, (bf16)vb[r].w };
            int byte = row * (BK * 2) + ((scol * 2) ^ ((row & 7) << 4));
            *(bf16x4*)((char*)As + byte) = pa;
            *(bf16x4*)((char*)Bs + byte) = pb;
        }
        __syncthreads();

        for (int kti = 0; kti < K_DIM / BK; ++kti) {
            const int p = kti & 1;
            if (kti < K_DIM / BK - 1) {        // T14: issue next loads early
                const int kt = (kti + 1) * BK;
                #pragma unroll
                for (int r = 0; r < 8; ++r) {
                    int row = r * 16 + srow;
                    va[r] = *(const f32x4*)(xg + (long)row * K_DIM + kt + scol);
                    vb[r] = *(const f32x4*)(W  + (long)row * K_DIM + kt + scol);
                }
            }
            const char* Ap = (const char*)As + p * 16384;
            const char* Bp = (const char*)Bs + p * 16384;
            #pragma unroll
            for (int kk = 0; kk < 2; ++kk) {
                bf16x8 af[4], bg[4];
                #pragma unroll
                for (int m = 0; m < 4; ++m) {
                    int row  = wr * 64 + m * 16 + fr;
                    int byte = row * (BK * 2) + (((kk * 32 + fq * 8) * 2) ^ ((row & 7) << 4));
                    af[m] = *(const bf16x8*)(Ap + byte);
                }
                #pragma unroll
                for (int n = 0; n < 4; ++n) {
                    int row  = wc * 64 + n * 16 + fr;
                    int byte = row * (BK * 2) + (((kk * 32 + fq * 8) * 2) ^ ((row & 7) << 4));
                    bg[n] = *(const bf16x8*)(Bp + byte);
                }
                #pragma unroll
                for (int m = 0; m < 4; ++m)
                    #pragma unroll
                    for (int n = 0; n < 4; ++n)
                        acc[m][n] = __builtin_amdgcn_mfma_f32_16x16x32_bf16(
                            af[m], bg[n], acc[m][n], 0, 0, 0);
            }
            if (kti < K_DIM / BK - 1) {        // write-late into buf p^1
                #pragma unroll
                for (int r = 0; r < 8; ++r) {
                    int row = r * 16 + srow;
                    bf16x4 pa = { (bf16)va[r].x, (bf16)va[r].y, (bf16)va[r].z, (bf16)va[r].w };
                    bf16x4 pb = { (bf16)vb[r].x, (bf16)vb[r].y, (bf16)vb[r].z, (bf16)vb[r].w };
                    int byte = row * (BK * 2) + ((scol * 2) ^ ((row & 7) << 4));
                    *(bf16x4*)((char*)As + (p ^ 1) * 16384 + byte) = pa;
                    *(bf16x4*)((char*)Bs + (p ^ 1) * 16384 + byte) = pb;
                }
                __syncthreads();
            }
        }

        // ---- epilogue: As/Bs dead -> lsum/lcnt live. ----------------------
        __syncthreads();                       // all MFMA LDS reads complete
        for (int i = t; i < C_CLS * E_DIM; i += 256) lsum[i] = 0.f;
        if (t < C_CLS) lcnt[t] = 0.f;
        if (t < BM)    lr[t]   = 0.f;
        __syncthreads();

        // counts for this tile's 128 rows
        if (t < BM) atomicAdd(&lcnt[ly[rep * 128 + t]], 1.f);

        // C/D layout: col = wc*64+n*16+fr, row = wr*64+m*16+fq*4+j
        #pragma unroll
        for (int m = 0; m < 4; ++m) {
            #pragma unroll
            for (int j = 0; j < 4; ++j) {
                int  lrow = wr * 64 + m * 16 + fq * 4 + j;
                long grow = blockRow + lrow;
                int  cls  = ly[rep * 128 + lrow];
                float s = 0.f;
                #pragma unroll
                for (int n = 0; n < 4; ++n) {
                    float v = acc[m][n][j] + bvv[n];
                    outb[grow * E_DIM + wc * 64 + n * 16 + fr] = (bf16)v;
                    s += v * v;
                    atomicAdd(&lsum[cls * E_DIM + wc * 64 + n * 16 + fr], v);
                }
                s += __shfl_xor(s, 1); s += __shfl_xor(s, 2);
                s += __shfl_xor(s, 4); s += __shfl_xor(s, 8);
                if (fr == 0) atomicAdd(&lr[lrow], s);
            }
        }
        __syncthreads();

        // writeout: per-tile partials + rnorm
        for (int i = t; i < C_CLS * E_DIM; i += 256)
            pw[(long)tile * (C_CLS * E_DIM) + i] = lsum[i];
        if (t < C_CLS) pc[tile * C_CLS + t] = lcnt[t];
        if (t < BM)    rnorm[blockRow + t]  = lr[t];
    }
}

// -------------------- Kernel B: reduce + centroids + norms (64 blocks) -----
__global__ __launch_bounds__(256)
void centroid_kernel(const float* __restrict__ pw, const float* __restrict__ pc,
                     const float* __restrict__ centroid0,
                     float* __restrict__ cent, float* __restrict__ cnorm)
{
    __shared__ float scr[256];
    __shared__ float sumv[128];
    const int c = blockIdx.x;
    const int t = threadIdx.x;

    // count for class c over 1024 tile-partials
    {
        float s = 0.f;
        #pragma unroll
        for (int k = 0; k < 4; ++k) s += pc[(t * 4 + k) * C_CLS + c];
        scr[t] = s;
        __syncthreads();
        #pragma unroll
        for (int st = 128; st > 0; st >>= 1) {
            if (t < st) scr[t] += scr[t + st];
            __syncthreads();
        }
    }
    const float cnt = scr[0];
    __syncthreads();

    // sums for class c: dim e = t&127, j-half = t>>7
    {
        const int e = t & 127, half = t >> 7;
        float s = 0.f;
        for (int j = half * 512; j < half * 512 + 512; ++j)
            s += pw[(long)j * (C_CLS * E_DIM) + c * E_DIM + e];
        scr[t] = s;
        __syncthreads();
        if (t < 128) {
            float v = centroid0[c * E_DIM + t] + (scr[t] + scr[t + 128]) / cnt;
            cent[c * E_DIM + t] = v;
            sumv[t] = v * v;
        }
    }
    __syncthreads();
    if (t < 64) sumv[t] += sumv[t + 64];
    __syncthreads();
    if (t < 32) sumv[t] += sumv[t + 32];
    __syncthreads();
    if (t == 0) {
        float s = 0.f;
        #pragma unroll
        for (int k = 0; k < 32; ++k) s += sumv[k];
        cnorm[c] = s;
    }
}

// -------------------- Kernel C: dist + sigmoid (+ fused proto) -------------
__global__ __launch_bounds__(256, 4)
void dist_kernel(const bf16* __restrict__ outb, const float* __restrict__ cent,
                 const float* __restrict__ cnorm, const float* __restrict__ rnorm,
                 float* __restrict__ out0, float* __restrict__ proto)
{
    __shared__ float smemf[C_CLS * 129 + C_CLS + 128];
    const int t = threadIdx.x;

    if (blockIdx.x >= DIST_BLOCKS) {
        float* scf   = smemf;                    // [64][129]
        float* pnorm = smemf + C_CLS * 129;
        for (int idx = t; idx < C_CLS * E_DIM; idx += 256)
            scf[(idx >> 7) * 129 + (idx & 127)] = cent[idx];
        if (t < C_CLS) pnorm[t] = cnorm[t];
        __syncthreads();
        int p = (blockIdx.x - DIST_BLOCKS) * 256 + t;
        int i = p >> 6, j = p & 63;
        float d = 0.f;
        #pragma unroll 4
        for (int e = 0; e < E_DIM; ++e)
            d += scf[i * 129 + e] * scf[j * 129 + e];
        float d2 = pnorm[i] + pnorm[j] - 2.f * d;
        proto[p] = __expf(-0.5f * sqrtf(fmaxf(d2, 1e-12f)));
        return;
    }

    bf16*  Cs     = (bf16*)smemf;                // [64][128] bf16, swizzled
    float* snorm  = smemf + C_CLS * 129;
    float* srnorm = snorm + C_CLS;
    {
        int srw = t >> 5;
        int scl = (t & 31) * 4;
        #pragma unroll
        for (int r = 0; r < 8; ++r) {
            int row = r * 8 + srw;
            f32x4 v = *(const f32x4*)(cent + row * E_DIM + scl);
            bf16x4 pv = { (bf16)v.x, (bf16)v.y, (bf16)v.z, (bf16)v.w };
            int byte = row * (E_DIM * 2) + ((scl * 2) ^ ((row & 7) << 4));
            *(bf16x4*)((char*)Cs + byte) = pv;
        }
        if (t < C_CLS) snorm[t] = cnorm[t];
        if (t < 32) ((f32x4*)srnorm)[t] =
            ((const f32x4*)(rnorm + (long)blockIdx.x * 128))[t];
    }
    const int lane = t & 63;
    const int w    = t >> 6;
    const int fr   = lane & 15;
    const int fq   = lane >> 4;
    const long blkrow = (long)blockIdx.x * 128;
    f32x4 acc[2][4] = {};
    __syncthreads();
    #pragma unroll
    for (int kt = 0; kt < 4; ++kt) {
        bf16x8 af[2];
        #pragma unroll
        for (int m = 0; m < 2; ++m) {
            long row = blkrow + w * 32 + m * 16 + fr;
            af[m] = *(const bf16x8*)(outb + row * E_DIM + kt * 32 + fq * 8);
        }
        #pragma unroll
        for (int n = 0; n < 4; ++n) {
            int row  = n * 16 + fr;
            int byte = row * (E_DIM * 2) + (((kt * 32 + fq * 8) * 2) ^ ((row & 7) << 4));
            bf16x8 bq = *(const bf16x8*)((const char*)Cs + byte);
            acc[0][n] = __builtin_amdgcn_mfma_f32_16x16x32_bf16(af[0], bq, acc[0][n], 0, 0, 0);
            acc[1][n] = __builtin_amdgcn_mfma_f32_16x16x32_bf16(af[1], bq, acc[1][n], 0, 0, 0);
        }
    }
    #pragma unroll
    for (int m = 0; m < 2; ++m) {
        #pragma unroll
        for (int n = 0; n < 4; ++n) {
            int gcol = n * 16 + fr;
            float cn = snorm[gcol];
            #pragma unroll
            for (int j = 0; j < 4; ++j) {
                int lrow = w * 32 + m * 16 + fq * 4 + j;
                float d2 = srnorm[lrow] + cn - 2.f * acc[m][n][j];
                float dist = sqrtf(fmaxf(d2, 1e-12f));
                float ez = __expf(-0.5f * dist);
                out0[(blkrow + lrow) * C_CLS + gcol] = 1.f / (1.f + __expf(-ez));
            }
        }
    }
}

// ---------------------------------------------------------------------------
extern "C" void kernel_launch(void* const* d_in, const int* in_sizes, int n_in,
                              void* d_out, int out_size, void* d_ws, size_t ws_size,
                              hipStream_t stream)
{
    const float* x         = (const float*)d_in[0];
    const int*   y         = (const int*)d_in[1];
    const float* W         = (const float*)d_in[2];
    const float* bias      = (const float*)d_in[3];
    const float* centroid0 = (const float*)d_in[4];

    char* ws = (char*)d_ws;
    bf16*  outb  = (bf16*)ws;                                   // 33,554,432 B
    float* rnorm = (float*)(ws + 33554432);                     //    524,288 B
    float* pw    = (float*)(ws + 34078720);                     // 33,554,432 B (1024*8192 f32)
    float* pc    = (float*)(ws + 67633152);                     //    262,144 B (1024*64)
    float* cent  = (float*)(ws + 67895296);                     //     32,768 B
    float* cnorm = (float*)(ws + 67928064);                     //        256 B

    float* out0  = (float*)d_out;
    float* proto = out0 + (long)B_ROWS * C_CLS;

    gemmseg_kernel <<<GRID_A, 256, 0, stream>>>(x, y, W, bias, outb, rnorm, pw, pc);
    centroid_kernel<<<C_CLS, 256, 0, stream>>>(pw, pc, centroid0, cent, cnorm);
    dist_kernel    <<<DIST_BLOCKS + PROTO_BLOCKS, 256, 0, stream>>>(
        outb, cent, cnorm, rnorm, out0, proto);
}

// Round 8
// 276.992 us; speedup vs baseline: 1.6013x; 1.0801x over previous
//
#include <hip/hip_runtime.h>
#include <math.h>

// ---------------------------------------------------------------------------
// ClusterML pipeline (round 8): revert to proven split kernels + merged
// centroid + DIAGNOSTIC dist x3.
//   r7 post-mortem: fusing per-class accumulation into the gemm epilogue cost
//   +125us with all pipes idle -> suspected flat-atomic fallback on char*-
//   carved LDS pointers. Reverted to r3's clean __shared__ kernels.
//   K1 gemm (r3 exact, 65-69us proven)          1024 blocks
//   K2 segsum (r3 exact, clean LDS atomics)      512 blocks
//   K3 centroid = reduce+counts+cent+cnorm        64 blocks (merged, -1 launch)
//   K4 dist+proto (r3 exact)  x3 DIAGNOSTIC     1040 blocks each
//   dist attribution next round: D+ovh = (dur_r8 - dur_r9)/2.
// ---------------------------------------------------------------------------

typedef __bf16 bf16;
typedef bf16  bf16x2 __attribute__((ext_vector_type(2)));
typedef bf16  bf16x4 __attribute__((ext_vector_type(4)));
typedef bf16  bf16x8 __attribute__((ext_vector_type(8)));
typedef float f32x4  __attribute__((ext_vector_type(4)));

#define B_ROWS 131072
#define K_DIM  512
#define E_DIM  128
#define C_CLS  64

#define BM 128
#define BK 64

#define SEG_BLOCKS 512
#define ROWS_PER_SEG (B_ROWS / SEG_BLOCKS)   // 256

#define DIST_BLOCKS (B_ROWS / 128)           // 1024
#define PROTO_BLOCKS 16

// -------------------- Kernel 1: gemm + rnorm (dbuf + T14; r3 exact) --------
__global__ __launch_bounds__(256, 2)
void gemm_kernel(const float* __restrict__ x, const float* __restrict__ W,
                 const float* __restrict__ bias, bf16* __restrict__ outb,
                 float* __restrict__ rnorm)
{
    __shared__ bf16 As[2][BM * BK];   // 2 x 16KB, XOR-swizzled rows
    __shared__ bf16 Bs[2][BM * BK];
    __shared__ float lr[BM];

    const int t    = threadIdx.x;
    const int lane = t & 63;
    const int w    = t >> 6;
    const int wr   = w >> 1;
    const int wc   = w & 1;
    const int fr   = lane & 15;
    const int fq   = lane >> 4;
    const long blockRow = (long)blockIdx.x * BM;

    const int srow = t >> 4;          // 0..15
    const int scol = (t & 15) * 4;    // 0..60

    f32x4 acc[4][4] = {};
    f32x4 va[8], vb[8];

    const float* xg = x + blockRow * K_DIM;
    if (t < BM) lr[t] = 0.f;

    #pragma unroll
    for (int r = 0; r < 8; ++r) {
        int row = r * 16 + srow;
        va[r] = *(const f32x4*)(xg + (long)row * K_DIM + scol);
        vb[r] = *(const f32x4*)(W  + (long)row * K_DIM + scol);
    }
    #pragma unroll
    for (int r = 0; r < 8; ++r) {
        int row = r * 16 + srow;
        bf16x4 pa = { (bf16)va[r].x, (bf16)va[r].y, (bf16)va[r].z, (bf16)va[r].w };
        bf16x4 pb = { (bf16)vb[r].x, (bf16)vb[r].y, (bf16)vb[r].z, (bf16)vb[r].w };
        int byte = row * (BK * 2) + ((scol * 2) ^ ((row & 7) << 4));
        *(bf16x4*)((char*)As[0] + byte) = pa;
        *(bf16x4*)((char*)Bs[0] + byte) = pb;
    }
    __syncthreads();

    for (int kti = 0; kti < K_DIM / BK; ++kti) {
        const int p = kti & 1;
        if (kti < K_DIM / BK - 1) {
            const int kt = (kti + 1) * BK;
            #pragma unroll
            for (int r = 0; r < 8; ++r) {
                int row = r * 16 + srow;
                va[r] = *(const f32x4*)(xg + (long)row * K_DIM + kt + scol);
                vb[r] = *(const f32x4*)(W  + (long)row * K_DIM + kt + scol);
            }
        }
        const bf16* Ap = As[p];
        const bf16* Bp = Bs[p];
        #pragma unroll
        for (int kk = 0; kk < 2; ++kk) {
            bf16x8 af[4], bg[4];
            #pragma unroll
            for (int m = 0; m < 4; ++m) {
                int row  = wr * 64 + m * 16 + fr;
                int byte = row * (BK * 2) + (((kk * 32 + fq * 8) * 2) ^ ((row & 7) << 4));
                af[m] = *(const bf16x8*)((const char*)Ap + byte);
            }
            #pragma unroll
            for (int n = 0; n < 4; ++n) {
                int row  = wc * 64 + n * 16 + fr;
                int byte = row * (BK * 2) + (((kk * 32 + fq * 8) * 2) ^ ((row & 7) << 4));
                bg[n] = *(const bf16x8*)((const char*)Bp + byte);
            }
            #pragma unroll
            for (int m = 0; m < 4; ++m)
                #pragma unroll
                for (int n = 0; n < 4; ++n)
                    acc[m][n] = __builtin_amdgcn_mfma_f32_16x16x32_bf16(
                        af[m], bg[n], acc[m][n], 0, 0, 0);
        }
        if (kti < K_DIM / BK - 1) {
            #pragma unroll
            for (int r = 0; r < 8; ++r) {
                int row = r * 16 + srow;
                bf16x4 pa = { (bf16)va[r].x, (bf16)va[r].y, (bf16)va[r].z, (bf16)va[r].w };
                bf16x4 pb = { (bf16)vb[r].x, (bf16)vb[r].y, (bf16)vb[r].z, (bf16)vb[r].w };
                int byte = row * (BK * 2) + ((scol * 2) ^ ((row & 7) << 4));
                *(bf16x4*)((char*)As[p ^ 1] + byte) = pa;
                *(bf16x4*)((char*)Bs[p ^ 1] + byte) = pb;
            }
            __syncthreads();
        }
    }

    // epilogue: C/D layout col = lane&15, row = (lane>>4)*4 + j
    float bvv[4];
    #pragma unroll
    for (int n = 0; n < 4; ++n) bvv[n] = bias[wc * 64 + n * 16 + fr];

    #pragma unroll
    for (int m = 0; m < 4; ++m) {
        #pragma unroll
        for (int j = 0; j < 4; ++j) {
            long grow = blockRow + wr * 64 + m * 16 + fq * 4 + j;
            float s = 0.f;
            #pragma unroll
            for (int n = 0; n < 4; ++n) {
                float v = acc[m][n][j] + bvv[n];
                outb[grow * E_DIM + wc * 64 + n * 16 + fr] = (bf16)v;
                s += v * v;
            }
            s += __shfl_xor(s, 1); s += __shfl_xor(s, 2);
            s += __shfl_xor(s, 4); s += __shfl_xor(s, 8);
            if (fr == 0) atomicAdd(&lr[wr * 64 + m * 16 + fq * 4 + j], s);
        }
    }
    __syncthreads();
    if (t < BM) rnorm[blockRow + t] = lr[t];
}

// -------------------- Kernel 2: per-class partial sums (r3 exact) ----------
__global__ __launch_bounds__(256)
void segsum_kernel(const bf16* __restrict__ outb, const int* __restrict__ y,
                   float* __restrict__ pw, float* __restrict__ pc)
{
    __shared__ float lsum[C_CLS * E_DIM];
    __shared__ float lcnt[C_CLS];
    __shared__ int   ly[ROWS_PER_SEG];
    const int t = threadIdx.x;
    for (int i = t; i < C_CLS * E_DIM; i += 256) lsum[i] = 0.f;
    if (t < C_CLS) lcnt[t] = 0.f;
    const long base = (long)blockIdx.x * ROWS_PER_SEG;
    if (t < ROWS_PER_SEG) ly[t] = y[base + t];
    __syncthreads();
    const int w = t >> 6, lane = t & 63;
    #pragma unroll 4
    for (int i = w; i < ROWS_PER_SEG; i += 4) {
        int cls = ly[i];
        bf16x2 v = *(const bf16x2*)(outb + (base + i) * E_DIM + lane * 2);
        atomicAdd(&lsum[cls * E_DIM + lane * 2 + 0], (float)v[0]);
        atomicAdd(&lsum[cls * E_DIM + lane * 2 + 1], (float)v[1]);
        if (lane == 0) atomicAdd(&lcnt[cls], 1.f);
    }
    __syncthreads();
    for (int i = t; i < C_CLS * E_DIM; i += 256)
        pw[(long)blockIdx.x * (C_CLS * E_DIM) + i] = lsum[i];
    if (t < C_CLS) pc[blockIdx.x * C_CLS + t] = lcnt[t];
}

// ------------- Kernel 3: merged reduce + counts + centroids + norms --------
__global__ __launch_bounds__(256)
void centroid_kernel(const float* __restrict__ pw, const float* __restrict__ pc,
                     const float* __restrict__ centroid0,
                     float* __restrict__ cent, float* __restrict__ cnorm)
{
    __shared__ float scr[256];
    __shared__ float sumv[128];
    const int c = blockIdx.x;
    const int t = threadIdx.x;

    // count for class c over 512 tile-partials
    scr[t] = pc[t * C_CLS + c] + pc[(t + 256) * C_CLS + c];
    __syncthreads();
    #pragma unroll
    for (int st = 128; st > 0; st >>= 1) {
        if (t < st) scr[t] += scr[t + st];
        __syncthreads();
    }
    const float cnt = scr[0];
    __syncthreads();

    // sums for class c: dim e = t&127, half = t>>7 over 256 j's each
    {
        const int e = t & 127, half = t >> 7;
        float s = 0.f;
        for (int j = half * 256; j < half * 256 + 256; ++j)
            s += pw[(long)j * (C_CLS * E_DIM) + c * E_DIM + e];
        scr[t] = s;
        __syncthreads();
        if (t < 128) {
            float v = centroid0[c * E_DIM + t] + (scr[t] + scr[t + 128]) / cnt;
            cent[c * E_DIM + t] = v;
            sumv[t] = v * v;
        }
    }
    __syncthreads();
    if (t < 64) sumv[t] += sumv[t + 64];
    __syncthreads();
    if (t < 32) sumv[t] += sumv[t + 32];
    __syncthreads();
    if (t == 0) {
        float s = 0.f;
        #pragma unroll
        for (int k = 0; k < 32; ++k) s += sumv[k];
        cnorm[c] = s;
    }
}

// -------------------- Kernel 4: dist + sigmoid (+ fused proto; r3 exact) ---
__global__ __launch_bounds__(256, 4)
void dist_kernel(const bf16* __restrict__ outb, const float* __restrict__ cent,
                 const float* __restrict__ cnorm, const float* __restrict__ rnorm,
                 float* __restrict__ out0, float* __restrict__ proto)
{
    __shared__ float smemf[C_CLS * 129 + C_CLS + 128];
    const int t = threadIdx.x;

    if (blockIdx.x >= DIST_BLOCKS) {
        float* scf   = smemf;                    // [64][129]
        float* pnorm = smemf + C_CLS * 129;
        for (int idx = t; idx < C_CLS * E_DIM; idx += 256)
            scf[(idx >> 7) * 129 + (idx & 127)] = cent[idx];
        if (t < C_CLS) pnorm[t] = cnorm[t];
        __syncthreads();
        int p = (blockIdx.x - DIST_BLOCKS) * 256 + t;
        int i = p >> 6, j = p & 63;
        float d = 0.f;
        #pragma unroll 4
        for (int e = 0; e < E_DIM; ++e)
            d += scf[i * 129 + e] * scf[j * 129 + e];
        float d2 = pnorm[i] + pnorm[j] - 2.f * d;
        proto[p] = __expf(-0.5f * sqrtf(fmaxf(d2, 1e-12f)));
        return;
    }

    bf16*  Cs     = (bf16*)smemf;                // [64][128] bf16, swizzled
    float* snorm  = smemf + C_CLS * 129;
    float* srnorm = snorm + C_CLS;
    {
        int srw = t >> 5;
        int scl = (t & 31) * 4;
        #pragma unroll
        for (int r = 0; r < 8; ++r) {
            int row = r * 8 + srw;
            f32x4 v = *(const f32x4*)(cent + row * E_DIM + scl);
            bf16x4 pv = { (bf16)v.x, (bf16)v.y, (bf16)v.z, (bf16)v.w };
            int byte = row * (E_DIM * 2) + ((scl * 2) ^ ((row & 7) << 4));
            *(bf16x4*)((char*)Cs + byte) = pv;
        }
        if (t < C_CLS) snorm[t] = cnorm[t];
        if (t < 32) ((f32x4*)srnorm)[t] =
            ((const f32x4*)(rnorm + (long)blockIdx.x * 128))[t];
    }
    const int lane = t & 63;
    const int w    = t >> 6;
    const int fr   = lane & 15;
    const int fq   = lane >> 4;
    const long blkrow = (long)blockIdx.x * 128;
    f32x4 acc[2][4] = {};
    __syncthreads();
    #pragma unroll
    for (int kt = 0; kt < 4; ++kt) {
        bf16x8 af[2];
        #pragma unroll
        for (int m = 0; m < 2; ++m) {
            long row = blkrow + w * 32 + m * 16 + fr;
            af[m] = *(const bf16x8*)(outb + row * E_DIM + kt * 32 + fq * 8);
        }
        #pragma unroll
        for (int n = 0; n < 4; ++n) {
            int row  = n * 16 + fr;
            int byte = row * (E_DIM * 2) + (((kt * 32 + fq * 8) * 2) ^ ((row & 7) << 4));
            bf16x8 bq = *(const bf16x8*)((const char*)Cs + byte);
            acc[0][n] = __builtin_amdgcn_mfma_f32_16x16x32_bf16(af[0], bq, acc[0][n], 0, 0, 0);
            acc[1][n] = __builtin_amdgcn_mfma_f32_16x16x32_bf16(af[1], bq, acc[1][n], 0, 0, 0);
        }
    }
    #pragma unroll
    for (int m = 0; m < 2; ++m) {
        #pragma unroll
        for (int n = 0; n < 4; ++n) {
            int gcol = n * 16 + fr;
            float cn = snorm[gcol];
            #pragma unroll
            for (int j = 0; j < 4; ++j) {
                int lrow = w * 32 + m * 16 + fq * 4 + j;
                float d2 = srnorm[lrow] + cn - 2.f * acc[m][n][j];
                float dist = sqrtf(fmaxf(d2, 1e-12f));
                float ez = __expf(-0.5f * dist);
                out0[(blkrow + lrow) * C_CLS + gcol] = 1.f / (1.f + __expf(-ez));
            }
        }
    }
}

// ---------------------------------------------------------------------------
extern "C" void kernel_launch(void* const* d_in, const int* in_sizes, int n_in,
                              void* d_out, int out_size, void* d_ws, size_t ws_size,
                              hipStream_t stream)
{
    const float* x         = (const float*)d_in[0];
    const int*   y         = (const int*)d_in[1];
    const float* W         = (const float*)d_in[2];
    const float* bias      = (const float*)d_in[3];
    const float* centroid0 = (const float*)d_in[4];

    char* ws = (char*)d_ws;
    bf16*  outb  = (bf16*)ws;                                   // 33,554,432 B
    float* rnorm = (float*)(ws + 33554432);                     //    524,288 B
    float* pw    = (float*)(ws + 34078720);                     // 16,777,216 B
    float* pc    = (float*)(ws + 50855936);                     //    131,072 B
    float* cent  = (float*)(ws + 50987008);                     //     32,768 B
    float* cnorm = (float*)(ws + 51019776);                     //        256 B

    float* out0  = (float*)d_out;
    float* proto = out0 + (long)B_ROWS * C_CLS;

    gemm_kernel    <<<B_ROWS / BM, 256, 0, stream>>>(x, W, bias, outb, rnorm);
    segsum_kernel  <<<SEG_BLOCKS, 256, 0, stream>>>(outb, y, pw, pc);
    centroid_kernel<<<C_CLS, 256, 0, stream>>>(pw, pc, centroid0, cent, cnorm);
    // DIAGNOSTIC: dist x3 (idempotent). (dur_r8 - dur_r9)/2 = t_dist + ovh.
    dist_kernel    <<<DIST_BLOCKS + PROTO_BLOCKS, 256, 0, stream>>>(
        outb, cent, cnorm, rnorm, out0, proto);
    dist_kernel    <<<DIST_BLOCKS + PROTO_BLOCKS, 256, 0, stream>>>(
        outb, cent, cnorm, rnorm, out0, proto);
    dist_kernel    <<<DIST_BLOCKS + PROTO_BLOCKS, 256, 0, stream>>>(
        outb, cent, cnorm, rnorm, out0, proto);
}

// Round 9
// 245.549 us; speedup vs baseline: 1.8064x; 1.1281x over previous
//
#include <hip/hip_runtime.h>
#include <math.h>

// ---------------------------------------------------------------------------
// ClusterML pipeline (round 9 = round 8 with dist x1): attribution round.
//   r8: G + S + C + 3D = 277.0us  (S, C, G identical here)
//   r9: G + S + C + 1D  =>  D + ovh = (277.0 - dur_r9) / 2   [exact]
//   K1 gemm+rnorm (dbuf+T14)                 1024 blocks
//   K2 segsum partials (clean LDS atomics)    512 blocks
//   K3 merged reduce+counts+cent+cnorm         64 blocks
//   K4 dist+sigmoid+proto                    1040 blocks
// ---------------------------------------------------------------------------

typedef __bf16 bf16;
typedef bf16  bf16x2 __attribute__((ext_vector_type(2)));
typedef bf16  bf16x4 __attribute__((ext_vector_type(4)));
typedef bf16  bf16x8 __attribute__((ext_vector_type(8)));
typedef float f32x4  __attribute__((ext_vector_type(4)));

#define B_ROWS 131072
#define K_DIM  512
#define E_DIM  128
#define C_CLS  64

#define BM 128
#define BK 64

#define SEG_BLOCKS 512
#define ROWS_PER_SEG (B_ROWS / SEG_BLOCKS)   // 256

#define DIST_BLOCKS (B_ROWS / 128)           // 1024
#define PROTO_BLOCKS 16

// -------------------- Kernel 1: gemm + rnorm (dbuf + T14) ------------------
__global__ __launch_bounds__(256, 2)
void gemm_kernel(const float* __restrict__ x, const float* __restrict__ W,
                 const float* __restrict__ bias, bf16* __restrict__ outb,
                 float* __restrict__ rnorm)
{
    __shared__ bf16 As[2][BM * BK];   // 2 x 16KB, XOR-swizzled rows
    __shared__ bf16 Bs[2][BM * BK];
    __shared__ float lr[BM];

    const int t    = threadIdx.x;
    const int lane = t & 63;
    const int w    = t >> 6;
    const int wr   = w >> 1;
    const int wc   = w & 1;
    const int fr   = lane & 15;
    const int fq   = lane >> 4;
    const long blockRow = (long)blockIdx.x * BM;

    const int srow = t >> 4;          // 0..15
    const int scol = (t & 15) * 4;    // 0..60

    f32x4 acc[4][4] = {};
    f32x4 va[8], vb[8];

    const float* xg = x + blockRow * K_DIM;
    if (t < BM) lr[t] = 0.f;

    #pragma unroll
    for (int r = 0; r < 8; ++r) {
        int row = r * 16 + srow;
        va[r] = *(const f32x4*)(xg + (long)row * K_DIM + scol);
        vb[r] = *(const f32x4*)(W  + (long)row * K_DIM + scol);
    }
    #pragma unroll
    for (int r = 0; r < 8; ++r) {
        int row = r * 16 + srow;
        bf16x4 pa = { (bf16)va[r].x, (bf16)va[r].y, (bf16)va[r].z, (bf16)va[r].w };
        bf16x4 pb = { (bf16)vb[r].x, (bf16)vb[r].y, (bf16)vb[r].z, (bf16)vb[r].w };
        int byte = row * (BK * 2) + ((scol * 2) ^ ((row & 7) << 4));
        *(bf16x4*)((char*)As[0] + byte) = pa;
        *(bf16x4*)((char*)Bs[0] + byte) = pb;
    }
    __syncthreads();

    for (int kti = 0; kti < K_DIM / BK; ++kti) {
        const int p = kti & 1;
        if (kti < K_DIM / BK - 1) {
            const int kt = (kti + 1) * BK;
            #pragma unroll
            for (int r = 0; r < 8; ++r) {
                int row = r * 16 + srow;
                va[r] = *(const f32x4*)(xg + (long)row * K_DIM + kt + scol);
                vb[r] = *(const f32x4*)(W  + (long)row * K_DIM + kt + scol);
            }
        }
        const bf16* Ap = As[p];
        const bf16* Bp = Bs[p];
        #pragma unroll
        for (int kk = 0; kk < 2; ++kk) {
            bf16x8 af[4], bg[4];
            #pragma unroll
            for (int m = 0; m < 4; ++m) {
                int row  = wr * 64 + m * 16 + fr;
                int byte = row * (BK * 2) + (((kk * 32 + fq * 8) * 2) ^ ((row & 7) << 4));
                af[m] = *(const bf16x8*)((const char*)Ap + byte);
            }
            #pragma unroll
            for (int n = 0; n < 4; ++n) {
                int row  = wc * 64 + n * 16 + fr;
                int byte = row * (BK * 2) + (((kk * 32 + fq * 8) * 2) ^ ((row & 7) << 4));
                bg[n] = *(const bf16x8*)((const char*)Bp + byte);
            }
            #pragma unroll
            for (int m = 0; m < 4; ++m)
                #pragma unroll
                for (int n = 0; n < 4; ++n)
                    acc[m][n] = __builtin_amdgcn_mfma_f32_16x16x32_bf16(
                        af[m], bg[n], acc[m][n], 0, 0, 0);
        }
        if (kti < K_DIM / BK - 1) {
            #pragma unroll
            for (int r = 0; r < 8; ++r) {
                int row = r * 16 + srow;
                bf16x4 pa = { (bf16)va[r].x, (bf16)va[r].y, (bf16)va[r].z, (bf16)va[r].w };
                bf16x4 pb = { (bf16)vb[r].x, (bf16)vb[r].y, (bf16)vb[r].z, (bf16)vb[r].w };
                int byte = row * (BK * 2) + ((scol * 2) ^ ((row & 7) << 4));
                *(bf16x4*)((char*)As[p ^ 1] + byte) = pa;
                *(bf16x4*)((char*)Bs[p ^ 1] + byte) = pb;
            }
            __syncthreads();
        }
    }

    // epilogue: C/D layout col = lane&15, row = (lane>>4)*4 + j
    float bvv[4];
    #pragma unroll
    for (int n = 0; n < 4; ++n) bvv[n] = bias[wc * 64 + n * 16 + fr];

    #pragma unroll
    for (int m = 0; m < 4; ++m) {
        #pragma unroll
        for (int j = 0; j < 4; ++j) {
            long grow = blockRow + wr * 64 + m * 16 + fq * 4 + j;
            float s = 0.f;
            #pragma unroll
            for (int n = 0; n < 4; ++n) {
                float v = acc[m][n][j] + bvv[n];
                outb[grow * E_DIM + wc * 64 + n * 16 + fr] = (bf16)v;
                s += v * v;
            }
            s += __shfl_xor(s, 1); s += __shfl_xor(s, 2);
            s += __shfl_xor(s, 4); s += __shfl_xor(s, 8);
            if (fr == 0) atomicAdd(&lr[wr * 64 + m * 16 + fq * 4 + j], s);
        }
    }
    __syncthreads();
    if (t < BM) rnorm[blockRow + t] = lr[t];
}

// -------------------- Kernel 2: per-class partial sums ---------------------
__global__ __launch_bounds__(256)
void segsum_kernel(const bf16* __restrict__ outb, const int* __restrict__ y,
                   float* __restrict__ pw, float* __restrict__ pc)
{
    __shared__ float lsum[C_CLS * E_DIM];
    __shared__ float lcnt[C_CLS];
    __shared__ int   ly[ROWS_PER_SEG];
    const int t = threadIdx.x;
    for (int i = t; i < C_CLS * E_DIM; i += 256) lsum[i] = 0.f;
    if (t < C_CLS) lcnt[t] = 0.f;
    const long base = (long)blockIdx.x * ROWS_PER_SEG;
    if (t < ROWS_PER_SEG) ly[t] = y[base + t];
    __syncthreads();
    const int w = t >> 6, lane = t & 63;
    #pragma unroll 4
    for (int i = w; i < ROWS_PER_SEG; i += 4) {
        int cls = ly[i];
        bf16x2 v = *(const bf16x2*)(outb + (base + i) * E_DIM + lane * 2);
        atomicAdd(&lsum[cls * E_DIM + lane * 2 + 0], (float)v[0]);
        atomicAdd(&lsum[cls * E_DIM + lane * 2 + 1], (float)v[1]);
        if (lane == 0) atomicAdd(&lcnt[cls], 1.f);
    }
    __syncthreads();
    for (int i = t; i < C_CLS * E_DIM; i += 256)
        pw[(long)blockIdx.x * (C_CLS * E_DIM) + i] = lsum[i];
    if (t < C_CLS) pc[blockIdx.x * C_CLS + t] = lcnt[t];
}

// ------------- Kernel 3: merged reduce + counts + centroids + norms --------
__global__ __launch_bounds__(256)
void centroid_kernel(const float* __restrict__ pw, const float* __restrict__ pc,
                     const float* __restrict__ centroid0,
                     float* __restrict__ cent, float* __restrict__ cnorm)
{
    __shared__ float scr[256];
    __shared__ float sumv[128];
    const int c = blockIdx.x;
    const int t = threadIdx.x;

    // count for class c over 512 tile-partials
    scr[t] = pc[t * C_CLS + c] + pc[(t + 256) * C_CLS + c];
    __syncthreads();
    #pragma unroll
    for (int st = 128; st > 0; st >>= 1) {
        if (t < st) scr[t] += scr[t + st];
        __syncthreads();
    }
    const float cnt = scr[0];
    __syncthreads();

    // sums for class c: dim e = t&127, half = t>>7 over 256 j's each
    {
        const int e = t & 127, half = t >> 7;
        float s = 0.f;
        for (int j = half * 256; j < half * 256 + 256; ++j)
            s += pw[(long)j * (C_CLS * E_DIM) + c * E_DIM + e];
        scr[t] = s;
        __syncthreads();
        if (t < 128) {
            float v = centroid0[c * E_DIM + t] + (scr[t] + scr[t + 128]) / cnt;
            cent[c * E_DIM + t] = v;
            sumv[t] = v * v;
        }
    }
    __syncthreads();
    if (t < 64) sumv[t] += sumv[t + 64];
    __syncthreads();
    if (t < 32) sumv[t] += sumv[t + 32];
    __syncthreads();
    if (t == 0) {
        float s = 0.f;
        #pragma unroll
        for (int k = 0; k < 32; ++k) s += sumv[k];
        cnorm[c] = s;
    }
}

// -------------------- Kernel 4: dist + sigmoid (+ fused proto) -------------
__global__ __launch_bounds__(256, 4)
void dist_kernel(const bf16* __restrict__ outb, const float* __restrict__ cent,
                 const float* __restrict__ cnorm, const float* __restrict__ rnorm,
                 float* __restrict__ out0, float* __restrict__ proto)
{
    __shared__ float smemf[C_CLS * 129 + C_CLS + 128];
    const int t = threadIdx.x;

    if (blockIdx.x >= DIST_BLOCKS) {
        float* scf   = smemf;                    // [64][129]
        float* pnorm = smemf + C_CLS * 129;
        for (int idx = t; idx < C_CLS * E_DIM; idx += 256)
            scf[(idx >> 7) * 129 + (idx & 127)] = cent[idx];
        if (t < C_CLS) pnorm[t] = cnorm[t];
        __syncthreads();
        int p = (blockIdx.x - DIST_BLOCKS) * 256 + t;
        int i = p >> 6, j = p & 63;
        float d = 0.f;
        #pragma unroll 4
        for (int e = 0; e < E_DIM; ++e)
            d += scf[i * 129 + e] * scf[j * 129 + e];
        float d2 = pnorm[i] + pnorm[j] - 2.f * d;
        proto[p] = __expf(-0.5f * sqrtf(fmaxf(d2, 1e-12f)));
        return;
    }

    bf16*  Cs     = (bf16*)smemf;                // [64][128] bf16, swizzled
    float* snorm  = smemf + C_CLS * 129;
    float* srnorm = snorm + C_CLS;
    {
        int srw = t >> 5;
        int scl = (t & 31) * 4;
        #pragma unroll
        for (int r = 0; r < 8; ++r) {
            int row = r * 8 + srw;
            f32x4 v = *(const f32x4*)(cent + row * E_DIM + scl);
            bf16x4 pv = { (bf16)v.x, (bf16)v.y, (bf16)v.z, (bf16)v.w };
            int byte = row * (E_DIM * 2) + ((scl * 2) ^ ((row & 7) << 4));
            *(bf16x4*)((char*)Cs + byte) = pv;
        }
        if (t < C_CLS) snorm[t] = cnorm[t];
        if (t < 32) ((f32x4*)srnorm)[t] =
            ((const f32x4*)(rnorm + (long)blockIdx.x * 128))[t];
    }
    const int lane = t & 63;
    const int w    = t >> 6;
    const int fr   = lane & 15;
    const int fq   = lane >> 4;
    const long blkrow = (long)blockIdx.x * 128;
    f32x4 acc[2][4] = {};
    __syncthreads();
    #pragma unroll
    for (int kt = 0; kt < 4; ++kt) {
        bf16x8 af[2];
        #pragma unroll
        for (int m = 0; m < 2; ++m) {
            long row = blkrow + w * 32 + m * 16 + fr;
            af[m] = *(const bf16x8*)(outb + row * E_DIM + kt * 32 + fq * 8);
        }
        #pragma unroll
        for (int n = 0; n < 4; ++n) {
            int row  = n * 16 + fr;
            int byte = row * (E_DIM * 2) + (((kt * 32 + fq * 8) * 2) ^ ((row & 7) << 4));
            bf16x8 bq = *(const bf16x8*)((const char*)Cs + byte);
            acc[0][n] = __builtin_amdgcn_mfma_f32_16x16x32_bf16(af[0], bq, acc[0][n], 0, 0, 0);
            acc[1][n] = __builtin_amdgcn_mfma_f32_16x16x32_bf16(af[1], bq, acc[1][n], 0, 0, 0);
        }
    }
    #pragma unroll
    for (int m = 0; m < 2; ++m) {
        #pragma unroll
        for (int n = 0; n < 4; ++n) {
            int gcol = n * 16 + fr;
            float cn = snorm[gcol];
            #pragma unroll
            for (int j = 0; j < 4; ++j) {
                int lrow = w * 32 + m * 16 + fq * 4 + j;
                float d2 = srnorm[lrow] + cn - 2.f * acc[m][n][j];
                float dist = sqrtf(fmaxf(d2, 1e-12f));
                float ez = __expf(-0.5f * dist);
                out0[(blkrow + lrow) * C_CLS + gcol] = 1.f / (1.f + __expf(-ez));
            }
        }
    }
}

// ---------------------------------------------------------------------------
extern "C" void kernel_launch(void* const* d_in, const int* in_sizes, int n_in,
                              void* d_out, int out_size, void* d_ws, size_t ws_size,
                              hipStream_t stream)
{
    const float* x         = (const float*)d_in[0];
    const int*   y         = (const int*)d_in[1];
    const float* W         = (const float*)d_in[2];
    const float* bias      = (const float*)d_in[3];
    const float* centroid0 = (const float*)d_in[4];

    char* ws = (char*)d_ws;
    bf16*  outb  = (bf16*)ws;                                   // 33,554,432 B
    float* rnorm = (float*)(ws + 33554432);                     //    524,288 B
    float* pw    = (float*)(ws + 34078720);                     // 16,777,216 B
    float* pc    = (float*)(ws + 50855936);                     //    131,072 B
    float* cent  = (float*)(ws + 50987008);                     //     32,768 B
    float* cnorm = (float*)(ws + 51019776);                     //        256 B

    float* out0  = (float*)d_out;
    float* proto = out0 + (long)B_ROWS * C_CLS;

    gemm_kernel    <<<B_ROWS / BM, 256, 0, stream>>>(x, W, bias, outb, rnorm);
    segsum_kernel  <<<SEG_BLOCKS, 256, 0, stream>>>(outb, y, pw, pc);
    centroid_kernel<<<C_CLS, 256, 0, stream>>>(pw, pc, centroid0, cent, cnorm);
    dist_kernel    <<<DIST_BLOCKS + PROTO_BLOCKS, 256, 0, stream>>>(
        outb, cent, cnorm, rnorm, out0, proto);
}